// Round 1
// baseline (1773.672 us; speedup 1.0000x reference)
//
#include <hip/hip_runtime.h>

#define N_NODES 100000
#define N_EDGES 1000000
#define F_INF   128
#define HID     64
#define NLAY    6
#define NCLS    10
#define NGRAPH  64

// ---------------- degree / norm ----------------
__global__ void k_init_deg(float* deg, int n) {
    int i = blockIdx.x * blockDim.x + threadIdx.x;
    if (i < n) deg[i] = 1.0f;   // self-loop
}

__global__ void k_count_deg(const int* __restrict__ dst, float* deg, int e) {
    int i = blockIdx.x * blockDim.x + threadIdx.x;
    if (i < e) atomicAdd(&deg[dst[i]], 1.0f);
}

__global__ void k_rsqrt(float* deg, int n) {
    int i = blockIdx.x * blockDim.x + threadIdx.x;
    if (i < n) deg[i] = rsqrtf(deg[i]);   // deg >= 1 always
}

// ---------------- GEMM: C[n][64] = (A[n][K] @ W[K][64]) * disq[row] ----------------
// block = 256 threads, 64 rows per block. Thread: 4 rows x 4 cols.
__global__ __launch_bounds__(256) void k_gemm_scale(
    const float* __restrict__ A, int lda, int K,
    const float* __restrict__ W,          // [K][64] row-major
    const float* __restrict__ disq,       // row scale
    float* __restrict__ C,                // [n][64]
    int n)
{
    __shared__ float Ws[64 * 64];
    __shared__ float As[64 * 68];         // pad 68 to avoid bank conflicts
    const int tid  = threadIdx.x;
    const int col4 = (tid & 15) * 4;
    const int rowq = tid >> 4;            // 0..15 -> rows rowq*4 .. +3
    const int base = blockIdx.x * 64;

    float4 acc[4];
    #pragma unroll
    for (int r = 0; r < 4; r++) acc[r] = make_float4(0.f, 0.f, 0.f, 0.f);

    for (int k0 = 0; k0 < K; k0 += 64) {
        // stage W chunk (4096 floats) via float4
        #pragma unroll
        for (int i = tid; i < 1024; i += 256) {
            float4 v = *(const float4*)(W + (size_t)k0 * 64 + (size_t)i * 4);
            *(float4*)(Ws + i * 4) = v;
        }
        // stage A chunk: 64 rows x 64 k
        {
            int r  = tid >> 4;
            int c4 = (tid & 15) * 4;
            #pragma unroll
            for (int rr = 0; rr < 4; rr++) {
                int row = base + r + rr * 16;
                float4 v = make_float4(0.f, 0.f, 0.f, 0.f);
                if (row < n) v = *(const float4*)(A + (size_t)row * lda + k0 + c4);
                *(float4*)(As + (r + rr * 16) * 68 + c4) = v;
            }
        }
        __syncthreads();
        #pragma unroll 8
        for (int k = 0; k < 64; k++) {
            float4 w = *(const float4*)(Ws + k * 64 + col4);
            float a0 = As[(rowq * 4 + 0) * 68 + k];
            float a1 = As[(rowq * 4 + 1) * 68 + k];
            float a2 = As[(rowq * 4 + 2) * 68 + k];
            float a3 = As[(rowq * 4 + 3) * 68 + k];
            acc[0].x = fmaf(a0, w.x, acc[0].x); acc[0].y = fmaf(a0, w.y, acc[0].y);
            acc[0].z = fmaf(a0, w.z, acc[0].z); acc[0].w = fmaf(a0, w.w, acc[0].w);
            acc[1].x = fmaf(a1, w.x, acc[1].x); acc[1].y = fmaf(a1, w.y, acc[1].y);
            acc[1].z = fmaf(a1, w.z, acc[1].z); acc[1].w = fmaf(a1, w.w, acc[1].w);
            acc[2].x = fmaf(a2, w.x, acc[2].x); acc[2].y = fmaf(a2, w.y, acc[2].y);
            acc[2].z = fmaf(a2, w.z, acc[2].z); acc[2].w = fmaf(a2, w.w, acc[2].w);
            acc[3].x = fmaf(a3, w.x, acc[3].x); acc[3].y = fmaf(a3, w.y, acc[3].y);
            acc[3].z = fmaf(a3, w.z, acc[3].z); acc[3].w = fmaf(a3, w.w, acc[3].w);
        }
        __syncthreads();
    }

    #pragma unroll
    for (int r = 0; r < 4; r++) {
        int row = base + rowq * 4 + r;
        if (row < n) {
            float s = disq[row];
            float4 o;
            o.x = acc[r].x * s; o.y = acc[r].y * s;
            o.z = acc[r].z * s; o.w = acc[r].w * s;
            *(float4*)(C + (size_t)row * 64 + col4) = o;
        }
    }
}

// ---------------- propagate: agg[dst] += hW'[src], one wave per edge ----------------
__global__ __launch_bounds__(256) void k_prop(
    const int* __restrict__ src, const int* __restrict__ dst,
    const float* __restrict__ hW, float* __restrict__ agg, int e)
{
    const int lane = threadIdx.x & 63;
    int wid = blockIdx.x * 4 + (threadIdx.x >> 6);
    const int nw = gridDim.x * 4;
    for (int ed = wid; ed < e; ed += nw) {
        int s = src[ed];
        int d = dst[ed];
        float v = hW[(size_t)s * 64 + lane];
        atomicAdd(&agg[(size_t)d * 64 + lane], v);
    }
}

// ---------------- finalize: hcat[:,l*64+j] = relu(disq*(agg+hW') + b) ----------------
__global__ __launch_bounds__(256) void k_finalize(
    const float* __restrict__ agg, const float* __restrict__ hW,
    const float* __restrict__ disq, const float* __restrict__ bias,
    float* __restrict__ hcat_slice, int n)
{
    int idx = blockIdx.x * 256 + threadIdx.x;    // n*16 threads
    if (idx >= n * 16) return;
    int row = idx >> 4;
    int c4  = (idx & 15) * 4;
    float s = disq[row];
    float4 a = *(const float4*)(agg + (size_t)row * 64 + c4);
    float4 h = *(const float4*)(hW  + (size_t)row * 64 + c4);
    float4 b = *(const float4*)(bias + c4);
    float4 o;
    o.x = fmaxf(fmaf(s, a.x + h.x, b.x), 0.f);
    o.y = fmaxf(fmaf(s, a.y + h.y, b.y), 0.f);
    o.z = fmaxf(fmaf(s, a.z + h.z, b.z), 0.f);
    o.w = fmaxf(fmaf(s, a.w + h.w, b.w), 0.f);
    *(float4*)(hcat_slice + (size_t)row * 384 + c4) = o;
}

// ---------------- JK GEMM + bias + relu + graph pool (fused) ----------------
__global__ __launch_bounds__(256) void k_jk_pool(
    const float* __restrict__ A,          // hcat [n][384]
    const float* __restrict__ W,          // [384][64]
    const float* __restrict__ bias,       // [64]
    const int* __restrict__ batch,
    float* __restrict__ pooled,           // [64][64]
    int n)
{
    __shared__ float Ws[64 * 64];
    __shared__ float As[64 * 68];
    const int tid  = threadIdx.x;
    const int col4 = (tid & 15) * 4;
    const int rowq = tid >> 4;
    const int base = blockIdx.x * 64;

    float4 acc[4];
    #pragma unroll
    for (int r = 0; r < 4; r++) acc[r] = make_float4(0.f, 0.f, 0.f, 0.f);

    for (int k0 = 0; k0 < 384; k0 += 64) {
        #pragma unroll
        for (int i = tid; i < 1024; i += 256) {
            float4 v = *(const float4*)(W + (size_t)k0 * 64 + (size_t)i * 4);
            *(float4*)(Ws + i * 4) = v;
        }
        {
            int r  = tid >> 4;
            int c4 = (tid & 15) * 4;
            #pragma unroll
            for (int rr = 0; rr < 4; rr++) {
                int row = base + r + rr * 16;
                float4 v = make_float4(0.f, 0.f, 0.f, 0.f);
                if (row < n) v = *(const float4*)(A + (size_t)row * 384 + k0 + c4);
                *(float4*)(As + (r + rr * 16) * 68 + c4) = v;
            }
        }
        __syncthreads();
        #pragma unroll 8
        for (int k = 0; k < 64; k++) {
            float4 w = *(const float4*)(Ws + k * 64 + col4);
            float a0 = As[(rowq * 4 + 0) * 68 + k];
            float a1 = As[(rowq * 4 + 1) * 68 + k];
            float a2 = As[(rowq * 4 + 2) * 68 + k];
            float a3 = As[(rowq * 4 + 3) * 68 + k];
            acc[0].x = fmaf(a0, w.x, acc[0].x); acc[0].y = fmaf(a0, w.y, acc[0].y);
            acc[0].z = fmaf(a0, w.z, acc[0].z); acc[0].w = fmaf(a0, w.w, acc[0].w);
            acc[1].x = fmaf(a1, w.x, acc[1].x); acc[1].y = fmaf(a1, w.y, acc[1].y);
            acc[1].z = fmaf(a1, w.z, acc[1].z); acc[1].w = fmaf(a1, w.w, acc[1].w);
            acc[2].x = fmaf(a2, w.x, acc[2].x); acc[2].y = fmaf(a2, w.y, acc[2].y);
            acc[2].z = fmaf(a2, w.z, acc[2].z); acc[2].w = fmaf(a2, w.w, acc[2].w);
            acc[3].x = fmaf(a3, w.x, acc[3].x); acc[3].y = fmaf(a3, w.y, acc[3].y);
            acc[3].z = fmaf(a3, w.z, acc[3].z); acc[3].w = fmaf(a3, w.w, acc[3].w);
        }
        __syncthreads();
    }

    float4 bb = *(const float4*)(bias + col4);
    int   curg = -1;
    float4 s4 = make_float4(0.f, 0.f, 0.f, 0.f);
    #pragma unroll
    for (int r = 0; r < 4; r++) {
        int row = base + rowq * 4 + r;
        if (row < n) {
            float4 v;
            v.x = fmaxf(acc[r].x + bb.x, 0.f);
            v.y = fmaxf(acc[r].y + bb.y, 0.f);
            v.z = fmaxf(acc[r].z + bb.z, 0.f);
            v.w = fmaxf(acc[r].w + bb.w, 0.f);
            int g = batch[row];
            if (g != curg) {
                if (curg >= 0) {
                    atomicAdd(&pooled[curg * 64 + col4 + 0], s4.x);
                    atomicAdd(&pooled[curg * 64 + col4 + 1], s4.y);
                    atomicAdd(&pooled[curg * 64 + col4 + 2], s4.z);
                    atomicAdd(&pooled[curg * 64 + col4 + 3], s4.w);
                }
                curg = g; s4 = v;
            } else {
                s4.x += v.x; s4.y += v.y; s4.z += v.z; s4.w += v.w;
            }
        }
    }
    if (curg >= 0) {
        atomicAdd(&pooled[curg * 64 + col4 + 0], s4.x);
        atomicAdd(&pooled[curg * 64 + col4 + 1], s4.y);
        atomicAdd(&pooled[curg * 64 + col4 + 2], s4.z);
        atomicAdd(&pooled[curg * 64 + col4 + 3], s4.w);
    }
}

// ---------------- head: relu(pooled@W1+b1) @ W2 + b2 -> softmax ----------------
__global__ void k_head(
    const float* __restrict__ pooled,
    const float* __restrict__ W1, const float* __restrict__ b1,
    const float* __restrict__ W2, const float* __restrict__ b2,
    float* __restrict__ out)
{
    int g = threadIdx.x;          // 64 threads, one per graph
    float p[64];
    #pragma unroll
    for (int k = 0; k < 64; k++) p[k] = pooled[g * 64 + k];
    float h1[64];
    #pragma unroll
    for (int j = 0; j < 64; j++) {
        float acc = b1[j];
        #pragma unroll
        for (int k = 0; k < 64; k++) acc = fmaf(p[k], W1[k * 64 + j], acc);
        h1[j] = fmaxf(acc, 0.f);
    }
    float lg[10];
    float mx = -1e30f;
    #pragma unroll
    for (int c = 0; c < 10; c++) {
        float acc = b2[c];
        #pragma unroll
        for (int j = 0; j < 64; j++) acc = fmaf(h1[j], W2[j * 10 + c], acc);
        lg[c] = acc;
        mx = fmaxf(mx, acc);
    }
    float ssum = 0.f;
    #pragma unroll
    for (int c = 0; c < 10; c++) { lg[c] = __expf(lg[c] - mx); ssum += lg[c]; }
    float inv = 1.0f / ssum;
    #pragma unroll
    for (int c = 0; c < 10; c++) out[g * 10 + c] = lg[c] * inv;
}

extern "C" void kernel_launch(void* const* d_in, const int* in_sizes, int n_in,
                              void* d_out, int out_size, void* d_ws, size_t ws_size,
                              hipStream_t stream) {
    (void)in_sizes; (void)n_in; (void)out_size; (void)ws_size;
    const float* x     = (const float*)d_in[0];
    const int*   ei    = (const int*)d_in[1];     // [2][E]
    const int*   batch = (const int*)d_in[2];     // [N]
    const float* W0    = (const float*)d_in[3];
    const float* b0    = (const float*)d_in[4];
    const float* Wh    = (const float*)d_in[5];   // [5][64][64]
    const float* bh    = (const float*)d_in[6];   // [5][64]
    const float* jkW   = (const float*)d_in[7];   // [384][64]
    const float* jkb   = (const float*)d_in[8];
    const float* W1    = (const float*)d_in[9];
    const float* b1    = (const float*)d_in[10];
    const float* W2    = (const float*)d_in[11];
    const float* b2    = (const float*)d_in[12];

    const int* src = ei;
    const int* dst = ei + N_EDGES;

    float* ws     = (float*)d_ws;
    float* disq   = ws;                               // N (padded to 100352)
    float* hWb    = ws + 100352;                      // N*64
    float* agg    = hWb + (size_t)N_NODES * 64;       // N*64
    float* hcat   = agg + (size_t)N_NODES * 64;       // N*384
    float* pooled = hcat + (size_t)N_NODES * 384;     // 64*64

    // degrees -> disq
    k_init_deg<<<(N_NODES + 255) / 256, 256, 0, stream>>>(disq, N_NODES);
    k_count_deg<<<(N_EDGES + 255) / 256, 256, 0, stream>>>(dst, disq, N_EDGES);
    k_rsqrt<<<(N_NODES + 255) / 256, 256, 0, stream>>>(disq, N_NODES);

    const int gemm_grid = (N_NODES + 63) / 64;    // 1563
    for (int l = 0; l < NLAY; l++) {
        const float* A    = (l == 0) ? x : (hcat + (size_t)(l - 1) * 64);
        int          lda  = (l == 0) ? F_INF : 384;
        int          K    = (l == 0) ? F_INF : HID;
        const float* W    = (l == 0) ? W0 : (Wh + (size_t)(l - 1) * 64 * 64);
        const float* bias = (l == 0) ? b0 : (bh + (size_t)(l - 1) * 64);

        k_gemm_scale<<<gemm_grid, 256, 0, stream>>>(A, lda, K, W, disq, hWb, N_NODES);
        hipMemsetAsync(agg, 0, (size_t)N_NODES * 64 * sizeof(float), stream);
        k_prop<<<16384, 256, 0, stream>>>(src, dst, hWb, agg, N_EDGES);
        k_finalize<<<(N_NODES * 16 + 255) / 256, 256, 0, stream>>>(
            agg, hWb, disq, bias, hcat + (size_t)l * 64, N_NODES);
    }

    hipMemsetAsync(pooled, 0, 64 * 64 * sizeof(float), stream);
    k_jk_pool<<<gemm_grid, 256, 0, stream>>>(hcat, jkW, jkb, batch, pooled, N_NODES);
    k_head<<<1, 64, 0, stream>>>(pooled, W1, b1, W2, b2, (float*)d_out);
}

// Round 2
// 801.477 us; speedup vs baseline: 2.2130x; 2.2130x over previous
//
#include <hip/hip_runtime.h>

#define NN 100000
#define NE 1000000
#define F_INF 128
#define HID 64
#define NLAY 6
#define NCLS 10
#define NGRAPH 64

// ================= CSR build =================
__global__ void k_hist(const int* __restrict__ dst, int* __restrict__ counts, int e) {
    int i = blockIdx.x * 256 + threadIdx.x;
    if (i < e) atomicAdd(&counts[dst[i]], 1);
}

__global__ void k_blocksum(const int* __restrict__ counts, int* __restrict__ bsum, int n) {
    int i = blockIdx.x * 256 + threadIdx.x;
    int v = (i < n) ? counts[i] : 0;
    #pragma unroll
    for (int off = 32; off >= 1; off >>= 1) v += __shfl_down(v, off);
    __shared__ int ws[4];
    if ((threadIdx.x & 63) == 0) ws[threadIdx.x >> 6] = v;
    __syncthreads();
    if (threadIdx.x == 0) bsum[blockIdx.x] = ws[0] + ws[1] + ws[2] + ws[3];
}

__global__ void k_scanbsum(int* __restrict__ bsum, int nb) {   // 1 block, 512 thr
    __shared__ int sh[512];
    int t = threadIdx.x;
    int v = (t < nb) ? bsum[t] : 0;
    sh[t] = v; __syncthreads();
    for (int off = 1; off < 512; off <<= 1) {
        int x = (t >= off) ? sh[t - off] : 0;
        __syncthreads();
        sh[t] += x; __syncthreads();
    }
    if (t < nb) bsum[t] = sh[t] - v;   // exclusive
}

__global__ void k_scanwrite(const int* __restrict__ counts, const int* __restrict__ bsumx,
                            int* __restrict__ rowptr, int* __restrict__ wptr,
                            float* __restrict__ disq, int n, int e) {
    __shared__ int sh[256];
    int t = threadIdx.x;
    int i = blockIdx.x * 256 + t;
    int v = (i < n) ? counts[i] : 0;
    sh[t] = v; __syncthreads();
    for (int off = 1; off < 256; off <<= 1) {
        int x = (t >= off) ? sh[t - off] : 0;
        __syncthreads();
        sh[t] += x; __syncthreads();
    }
    int excl = sh[t] - v + bsumx[blockIdx.x];
    if (i < n) {
        rowptr[i] = excl;
        wptr[i]   = excl;
        disq[i]   = rsqrtf((float)(v + 1));   // +1 self-loop
    }
    if (i == 0) rowptr[n] = e;
}

__global__ void k_scatter(const int* __restrict__ src, const int* __restrict__ dst,
                          int* __restrict__ wptr, int* __restrict__ csr, int e) {
    int i = blockIdx.x * 256 + threadIdx.x;
    if (i < e) {
        int pos = atomicAdd(&wptr[dst[i]], 1);
        csr[pos] = src[i];
    }
}

// ============ GEMM: C[n][64] = (A[n][K] @ W[K][64]) * disq[row], reg-prefetch pipelined ============
__global__ __launch_bounds__(256) void k_gemm_scale(
    const float* __restrict__ A, int lda, int K,
    const float* __restrict__ W, const float* __restrict__ disq,
    float* __restrict__ C, int n)
{
    __shared__ float Ws[64 * 64];
    __shared__ float As[64 * 68];
    const int tid  = threadIdx.x;
    const int col4 = (tid & 15) * 4;
    const int rowq = tid >> 4;
    const int base = blockIdx.x * 64;

    float4 wreg[4], areg[4];
    #pragma unroll
    for (int i = 0; i < 4; i++)
        wreg[i] = *(const float4*)(W + (size_t)(i * 256 + tid) * 4);
    #pragma unroll
    for (int rr = 0; rr < 4; rr++) {
        int row = base + rowq + rr * 16;
        areg[rr] = make_float4(0.f, 0.f, 0.f, 0.f);
        if (row < n) areg[rr] = *(const float4*)(A + (size_t)row * lda + col4);
    }
    #pragma unroll
    for (int i = 0; i < 4; i++)
        *(float4*)(Ws + (size_t)(i * 256 + tid) * 4) = wreg[i];
    #pragma unroll
    for (int rr = 0; rr < 4; rr++)
        *(float4*)(As + (size_t)(rowq + rr * 16) * 68 + col4) = areg[rr];
    __syncthreads();

    float4 acc[4];
    #pragma unroll
    for (int r = 0; r < 4; r++) acc[r] = make_float4(0.f, 0.f, 0.f, 0.f);

    for (int k0 = 0; k0 < K; k0 += 64) {
        const bool more = (k0 + 64) < K;
        if (more) {   // issue next-chunk global loads; latency hides under compute
            #pragma unroll
            for (int i = 0; i < 4; i++)
                wreg[i] = *(const float4*)(W + (size_t)(k0 + 64) * 64 + (i * 256 + tid) * 4);
            #pragma unroll
            for (int rr = 0; rr < 4; rr++) {
                int row = base + rowq + rr * 16;
                areg[rr] = make_float4(0.f, 0.f, 0.f, 0.f);
                if (row < n) areg[rr] = *(const float4*)(A + (size_t)row * lda + k0 + 64 + col4);
            }
        }
        #pragma unroll 8
        for (int k = 0; k < 64; k++) {
            float4 w = *(const float4*)(Ws + k * 64 + col4);
            float a0 = As[(rowq * 4 + 0) * 68 + k];
            float a1 = As[(rowq * 4 + 1) * 68 + k];
            float a2 = As[(rowq * 4 + 2) * 68 + k];
            float a3 = As[(rowq * 4 + 3) * 68 + k];
            acc[0].x = fmaf(a0, w.x, acc[0].x); acc[0].y = fmaf(a0, w.y, acc[0].y);
            acc[0].z = fmaf(a0, w.z, acc[0].z); acc[0].w = fmaf(a0, w.w, acc[0].w);
            acc[1].x = fmaf(a1, w.x, acc[1].x); acc[1].y = fmaf(a1, w.y, acc[1].y);
            acc[1].z = fmaf(a1, w.z, acc[1].z); acc[1].w = fmaf(a1, w.w, acc[1].w);
            acc[2].x = fmaf(a2, w.x, acc[2].x); acc[2].y = fmaf(a2, w.y, acc[2].y);
            acc[2].z = fmaf(a2, w.z, acc[2].z); acc[2].w = fmaf(a2, w.w, acc[2].w);
            acc[3].x = fmaf(a3, w.x, acc[3].x); acc[3].y = fmaf(a3, w.y, acc[3].y);
            acc[3].z = fmaf(a3, w.z, acc[3].z); acc[3].w = fmaf(a3, w.w, acc[3].w);
        }
        __syncthreads();
        if (more) {
            #pragma unroll
            for (int i = 0; i < 4; i++)
                *(float4*)(Ws + (size_t)(i * 256 + tid) * 4) = wreg[i];
            #pragma unroll
            for (int rr = 0; rr < 4; rr++)
                *(float4*)(As + (size_t)(rowq + rr * 16) * 68 + col4) = areg[rr];
            __syncthreads();
        }
    }

    #pragma unroll
    for (int r = 0; r < 4; r++) {
        int row = base + rowq * 4 + r;
        if (row < n) {
            float s = disq[row];
            float4 o;
            o.x = acc[r].x * s; o.y = acc[r].y * s;
            o.z = acc[r].z * s; o.w = acc[r].w * s;
            *(float4*)(C + (size_t)row * 64 + col4) = o;
        }
    }
}

// ============ gather-aggregate + finalize: one wave per node ============
__global__ __launch_bounds__(256) void k_gather(
    const int* __restrict__ rowptr, const int* __restrict__ csr,
    const float* __restrict__ hW, const float* __restrict__ disq,
    const float* __restrict__ bias, float* __restrict__ out_slice, int n)
{
    int wid  = (blockIdx.x * 256 + threadIdx.x) >> 6;
    int lane = threadIdx.x & 63;
    if (wid >= n) return;
    int j  = rowptr[wid];
    int r1 = rowptr[wid + 1];
    float v = hW[(size_t)wid * 64 + lane];      // self-loop (already * disq[wid])
    while (j < r1) {
        int cnt = min(r1 - j, 64);
        int idx = (lane < cnt) ? csr[j + lane] : 0;
        int jj = 0;
        for (; jj + 4 <= cnt; jj += 4) {
            int s0 = __shfl(idx, jj + 0), s1 = __shfl(idx, jj + 1);
            int s2 = __shfl(idx, jj + 2), s3 = __shfl(idx, jj + 3);
            float v0 = hW[(size_t)s0 * 64 + lane];
            float v1 = hW[(size_t)s1 * 64 + lane];
            float v2 = hW[(size_t)s2 * 64 + lane];
            float v3 = hW[(size_t)s3 * 64 + lane];
            v += v0 + v1 + v2 + v3;
        }
        for (; jj < cnt; jj++) {
            int s = __shfl(idx, jj);
            v += hW[(size_t)s * 64 + lane];
        }
        j += cnt;
    }
    float o = fmaxf(fmaf(disq[wid], v, bias[lane]), 0.f);
    out_slice[(size_t)wid * 384 + lane] = o;
}

// ============ JK GEMM + bias + relu + pool, pipelined ============
__global__ __launch_bounds__(256) void k_jk_pool(
    const float* __restrict__ A, const float* __restrict__ W,
    const float* __restrict__ bias, const int* __restrict__ batch,
    float* __restrict__ pooled, int n)
{
    __shared__ float Ws[64 * 64];
    __shared__ float As[64 * 68];
    const int tid  = threadIdx.x;
    const int col4 = (tid & 15) * 4;
    const int rowq = tid >> 4;
    const int base = blockIdx.x * 64;

    float4 wreg[4], areg[4];
    #pragma unroll
    for (int i = 0; i < 4; i++)
        wreg[i] = *(const float4*)(W + (size_t)(i * 256 + tid) * 4);
    #pragma unroll
    for (int rr = 0; rr < 4; rr++) {
        int row = base + rowq + rr * 16;
        areg[rr] = make_float4(0.f, 0.f, 0.f, 0.f);
        if (row < n) areg[rr] = *(const float4*)(A + (size_t)row * 384 + col4);
    }
    #pragma unroll
    for (int i = 0; i < 4; i++)
        *(float4*)(Ws + (size_t)(i * 256 + tid) * 4) = wreg[i];
    #pragma unroll
    for (int rr = 0; rr < 4; rr++)
        *(float4*)(As + (size_t)(rowq + rr * 16) * 68 + col4) = areg[rr];
    __syncthreads();

    float4 acc[4];
    #pragma unroll
    for (int r = 0; r < 4; r++) acc[r] = make_float4(0.f, 0.f, 0.f, 0.f);

    for (int k0 = 0; k0 < 384; k0 += 64) {
        const bool more = (k0 + 64) < 384;
        if (more) {
            #pragma unroll
            for (int i = 0; i < 4; i++)
                wreg[i] = *(const float4*)(W + (size_t)(k0 + 64) * 64 + (i * 256 + tid) * 4);
            #pragma unroll
            for (int rr = 0; rr < 4; rr++) {
                int row = base + rowq + rr * 16;
                areg[rr] = make_float4(0.f, 0.f, 0.f, 0.f);
                if (row < n) areg[rr] = *(const float4*)(A + (size_t)row * 384 + k0 + 64 + col4);
            }
        }
        #pragma unroll 8
        for (int k = 0; k < 64; k++) {
            float4 w = *(const float4*)(Ws + k * 64 + col4);
            float a0 = As[(rowq * 4 + 0) * 68 + k];
            float a1 = As[(rowq * 4 + 1) * 68 + k];
            float a2 = As[(rowq * 4 + 2) * 68 + k];
            float a3 = As[(rowq * 4 + 3) * 68 + k];
            acc[0].x = fmaf(a0, w.x, acc[0].x); acc[0].y = fmaf(a0, w.y, acc[0].y);
            acc[0].z = fmaf(a0, w.z, acc[0].z); acc[0].w = fmaf(a0, w.w, acc[0].w);
            acc[1].x = fmaf(a1, w.x, acc[1].x); acc[1].y = fmaf(a1, w.y, acc[1].y);
            acc[1].z = fmaf(a1, w.z, acc[1].z); acc[1].w = fmaf(a1, w.w, acc[1].w);
            acc[2].x = fmaf(a2, w.x, acc[2].x); acc[2].y = fmaf(a2, w.y, acc[2].y);
            acc[2].z = fmaf(a2, w.z, acc[2].z); acc[2].w = fmaf(a2, w.w, acc[2].w);
            acc[3].x = fmaf(a3, w.x, acc[3].x); acc[3].y = fmaf(a3, w.y, acc[3].y);
            acc[3].z = fmaf(a3, w.z, acc[3].z); acc[3].w = fmaf(a3, w.w, acc[3].w);
        }
        __syncthreads();
        if (more) {
            #pragma unroll
            for (int i = 0; i < 4; i++)
                *(float4*)(Ws + (size_t)(i * 256 + tid) * 4) = wreg[i];
            #pragma unroll
            for (int rr = 0; rr < 4; rr++)
                *(float4*)(As + (size_t)(rowq + rr * 16) * 68 + col4) = areg[rr];
            __syncthreads();
        }
    }

    float4 bb = *(const float4*)(bias + col4);
    int curg = -1;
    float4 s4 = make_float4(0.f, 0.f, 0.f, 0.f);
    #pragma unroll
    for (int r = 0; r < 4; r++) {
        int row = base + rowq * 4 + r;
        if (row < n) {
            float4 vv;
            vv.x = fmaxf(acc[r].x + bb.x, 0.f);
            vv.y = fmaxf(acc[r].y + bb.y, 0.f);
            vv.z = fmaxf(acc[r].z + bb.z, 0.f);
            vv.w = fmaxf(acc[r].w + bb.w, 0.f);
            int g = batch[row];
            if (g != curg) {
                if (curg >= 0) {
                    atomicAdd(&pooled[curg * 64 + col4 + 0], s4.x);
                    atomicAdd(&pooled[curg * 64 + col4 + 1], s4.y);
                    atomicAdd(&pooled[curg * 64 + col4 + 2], s4.z);
                    atomicAdd(&pooled[curg * 64 + col4 + 3], s4.w);
                }
                curg = g; s4 = vv;
            } else {
                s4.x += vv.x; s4.y += vv.y; s4.z += vv.z; s4.w += vv.w;
            }
        }
    }
    if (curg >= 0) {
        atomicAdd(&pooled[curg * 64 + col4 + 0], s4.x);
        atomicAdd(&pooled[curg * 64 + col4 + 1], s4.y);
        atomicAdd(&pooled[curg * 64 + col4 + 2], s4.z);
        atomicAdd(&pooled[curg * 64 + col4 + 3], s4.w);
    }
}

// ============ head ============
__global__ void k_head(
    const float* __restrict__ pooled,
    const float* __restrict__ W1, const float* __restrict__ b1,
    const float* __restrict__ W2, const float* __restrict__ b2,
    float* __restrict__ out)
{
    int g = threadIdx.x;
    float p[64];
    #pragma unroll
    for (int k = 0; k < 64; k++) p[k] = pooled[g * 64 + k];
    float h1[64];
    #pragma unroll
    for (int j = 0; j < 64; j++) {
        float acc = b1[j];
        #pragma unroll
        for (int k = 0; k < 64; k++) acc = fmaf(p[k], W1[k * 64 + j], acc);
        h1[j] = fmaxf(acc, 0.f);
    }
    float lg[10];
    float mx = -1e30f;
    #pragma unroll
    for (int c = 0; c < 10; c++) {
        float acc = b2[c];
        #pragma unroll
        for (int j = 0; j < 64; j++) acc = fmaf(h1[j], W2[j * 10 + c], acc);
        lg[c] = acc;
        mx = fmaxf(mx, acc);
    }
    float ssum = 0.f;
    #pragma unroll
    for (int c = 0; c < 10; c++) { lg[c] = __expf(lg[c] - mx); ssum += lg[c]; }
    float inv = 1.0f / ssum;
    #pragma unroll
    for (int c = 0; c < 10; c++) out[g * 10 + c] = lg[c] * inv;
}

extern "C" void kernel_launch(void* const* d_in, const int* in_sizes, int n_in,
                              void* d_out, int out_size, void* d_ws, size_t ws_size,
                              hipStream_t stream) {
    (void)in_sizes; (void)n_in; (void)out_size; (void)ws_size;
    const float* x     = (const float*)d_in[0];
    const int*   ei    = (const int*)d_in[1];
    const int*   batch = (const int*)d_in[2];
    const float* W0    = (const float*)d_in[3];
    const float* b0    = (const float*)d_in[4];
    const float* Wh    = (const float*)d_in[5];
    const float* bh    = (const float*)d_in[6];
    const float* jkW   = (const float*)d_in[7];
    const float* jkb   = (const float*)d_in[8];
    const float* W1    = (const float*)d_in[9];
    const float* b1    = (const float*)d_in[10];
    const float* W2    = (const float*)d_in[11];
    const float* b2    = (const float*)d_in[12];

    const int* src = ei;
    const int* dst = ei + NE;

    float* fws    = (float*)d_ws;
    float* disq   = fws;                               // 100352
    float* hWb    = disq + 100352;                     // NN*64
    float* hcat   = hWb + (size_t)NN * 64;             // NN*384
    float* pooled = hcat + (size_t)NN * 384;           // 4096
    int*   counts = (int*)(pooled + 4096);             // 100352
    int*   rowptr = counts + 100352;                   // 100352 (uses NN+1)
    int*   wptr   = rowptr + 100352;                   // 100352
    int*   bsum   = wptr + 100352;                     // 512
    int*   csr    = bsum + 512;                        // NE

    const int NB_N = (NN + 255) / 256;                 // 391
    const int NB_E = (NE + 255) / 256;                 // 3907

    // ---- CSR build (once per call) ----
    hipMemsetAsync(counts, 0, (size_t)NN * sizeof(int), stream);
    k_hist<<<NB_E, 256, 0, stream>>>(dst, counts, NE);
    k_blocksum<<<NB_N, 256, 0, stream>>>(counts, bsum, NN);
    k_scanbsum<<<1, 512, 0, stream>>>(bsum, NB_N);
    k_scanwrite<<<NB_N, 256, 0, stream>>>(counts, bsum, rowptr, wptr, disq, NN, NE);
    k_scatter<<<NB_E, 256, 0, stream>>>(src, dst, wptr, csr, NE);

    // ---- layers ----
    const int gemm_grid   = (NN + 63) / 64;            // 1563
    const int gather_grid = (NN + 3) / 4;              // 25000
    for (int l = 0; l < NLAY; l++) {
        const float* A    = (l == 0) ? x : (hcat + (size_t)(l - 1) * 64);
        int          lda  = (l == 0) ? F_INF : 384;
        int          K    = (l == 0) ? F_INF : HID;
        const float* W    = (l == 0) ? W0 : (Wh + (size_t)(l - 1) * 64 * 64);
        const float* bias = (l == 0) ? b0 : (bh + (size_t)(l - 1) * 64);

        k_gemm_scale<<<gemm_grid, 256, 0, stream>>>(A, lda, K, W, disq, hWb, NN);
        k_gather<<<gather_grid, 256, 0, stream>>>(rowptr, csr, hWb, disq, bias,
                                                  hcat + (size_t)l * 64, NN);
    }

    // ---- JK + pool + head ----
    hipMemsetAsync(pooled, 0, 64 * 64 * sizeof(float), stream);
    k_jk_pool<<<gemm_grid, 256, 0, stream>>>(hcat, jkW, jkb, batch, pooled, NN);
    k_head<<<1, 64, 0, stream>>>(pooled, W1, b1, W2, b2, (float*)d_out);
}

// Round 4
// 743.469 us; speedup vs baseline: 2.3857x; 1.0780x over previous
//
#include <hip/hip_runtime.h>

#define NN 100000
#define NE 1000000
#define F_INF 128
#define HID 64
#define NLAY 6
#define NCLS 10
#define NGRAPH 64

// ================= CSR build =================
__global__ void k_hist(const int* __restrict__ dst, int* __restrict__ counts, int e) {
    int i = blockIdx.x * 256 + threadIdx.x;
    if (i < e) atomicAdd(&counts[dst[i]], 1);
}

__global__ void k_blocksum(const int* __restrict__ counts, int* __restrict__ bsum, int n) {
    int i = blockIdx.x * 256 + threadIdx.x;
    int v = (i < n) ? counts[i] : 0;
    #pragma unroll
    for (int off = 32; off >= 1; off >>= 1) v += __shfl_down(v, off);
    __shared__ int ws[4];
    if ((threadIdx.x & 63) == 0) ws[threadIdx.x >> 6] = v;
    __syncthreads();
    if (threadIdx.x == 0) bsum[blockIdx.x] = ws[0] + ws[1] + ws[2] + ws[3];
}

__global__ void k_scanbsum(int* __restrict__ bsum, int nb) {   // 1 block, 512 thr
    __shared__ int sh[512];
    int t = threadIdx.x;
    int v = (t < nb) ? bsum[t] : 0;
    sh[t] = v; __syncthreads();
    for (int off = 1; off < 512; off <<= 1) {
        int x = (t >= off) ? sh[t - off] : 0;
        __syncthreads();
        sh[t] += x; __syncthreads();
    }
    if (t < nb) bsum[t] = sh[t] - v;   // exclusive
}

__global__ void k_scanwrite(const int* __restrict__ counts, const int* __restrict__ bsumx,
                            int* __restrict__ rowptr, int* __restrict__ wptr,
                            float* __restrict__ disq, int n, int e) {
    __shared__ int sh[256];
    int t = threadIdx.x;
    int i = blockIdx.x * 256 + t;
    int v = (i < n) ? counts[i] : 0;
    sh[t] = v; __syncthreads();
    for (int off = 1; off < 256; off <<= 1) {
        int x = (t >= off) ? sh[t - off] : 0;
        __syncthreads();
        sh[t] += x; __syncthreads();
    }
    int excl = sh[t] - v + bsumx[blockIdx.x];
    if (i < n) {
        rowptr[i] = excl;
        wptr[i]   = excl;
        disq[i]   = rsqrtf((float)(v + 1));   // +1 self-loop
    }
    if (i == 0) rowptr[n] = e;
}

__global__ void k_scatter(const int* __restrict__ src, const int* __restrict__ dst,
                          int* __restrict__ wptr, int* __restrict__ csr, int e) {
    int i = blockIdx.x * 256 + threadIdx.x;
    if (i < e) {
        int pos = atomicAdd(&wptr[dst[i]], 1);
        csr[pos] = src[i];
    }
}

// ============ dual GEMM: C = (A@W)*disq[row]; optionally jkacc (+)= A@jkw ============
__global__ __launch_bounds__(256) void k_gemm_dual(
    const float* __restrict__ A, int lda, int K,
    const float* __restrict__ W,
    const float* __restrict__ jkw,
    const float* __restrict__ disq,
    float* __restrict__ C,
    float* __restrict__ jkacc,
    int jk_mode, int n)
{
    __shared__ float Ws[64 * 64];
    __shared__ float Ws2[64 * 64];
    __shared__ float As[64 * 68];
    const int tid  = threadIdx.x;
    const int col4 = (tid & 15) * 4;
    const int rowq = tid >> 4;
    const int base = blockIdx.x * 64;

    {
        #pragma unroll
        for (int i = 0; i < 4; i++) {
            float4 v = *(const float4*)(W + (size_t)(i * 256 + tid) * 4);
            *(float4*)(Ws + (size_t)(i * 256 + tid) * 4) = v;
        }
        if (jk_mode) {
            #pragma unroll
            for (int i = 0; i < 4; i++) {
                float4 v = *(const float4*)(jkw + (size_t)(i * 256 + tid) * 4);
                *(float4*)(Ws2 + (size_t)(i * 256 + tid) * 4) = v;
            }
        }
        #pragma unroll
        for (int rr = 0; rr < 4; rr++) {
            int row = base + rowq + rr * 16;
            float4 v = make_float4(0.f, 0.f, 0.f, 0.f);
            if (row < n) v = *(const float4*)(A + (size_t)row * lda + col4);
            *(float4*)(As + (size_t)(rowq + rr * 16) * 68 + col4) = v;
        }
    }
    __syncthreads();

    float4 acc[4], acc2[4];
    #pragma unroll
    for (int r = 0; r < 4; r++) {
        acc[r]  = make_float4(0.f, 0.f, 0.f, 0.f);
        acc2[r] = make_float4(0.f, 0.f, 0.f, 0.f);
    }

    for (int k0 = 0; k0 < K; k0 += 64) {
        const bool more = (k0 + 64) < K;
        float4 wreg[4], areg[4];
        if (more) {
            #pragma unroll
            for (int i = 0; i < 4; i++)
                wreg[i] = *(const float4*)(W + (size_t)(k0 + 64) * 64 + (i * 256 + tid) * 4);
            #pragma unroll
            for (int rr = 0; rr < 4; rr++) {
                int row = base + rowq + rr * 16;
                areg[rr] = make_float4(0.f, 0.f, 0.f, 0.f);
                if (row < n) areg[rr] = *(const float4*)(A + (size_t)row * lda + k0 + 64 + col4);
            }
        }
        if (jk_mode && k0 == 0) {
            #pragma unroll 4
            for (int k = 0; k < 64; k++) {
                float4 w  = *(const float4*)(Ws  + k * 64 + col4);
                float4 w2 = *(const float4*)(Ws2 + k * 64 + col4);
                float a0 = As[(rowq * 4 + 0) * 68 + k];
                float a1 = As[(rowq * 4 + 1) * 68 + k];
                float a2 = As[(rowq * 4 + 2) * 68 + k];
                float a3 = As[(rowq * 4 + 3) * 68 + k];
                acc[0].x = fmaf(a0, w.x, acc[0].x); acc[0].y = fmaf(a0, w.y, acc[0].y);
                acc[0].z = fmaf(a0, w.z, acc[0].z); acc[0].w = fmaf(a0, w.w, acc[0].w);
                acc[1].x = fmaf(a1, w.x, acc[1].x); acc[1].y = fmaf(a1, w.y, acc[1].y);
                acc[1].z = fmaf(a1, w.z, acc[1].z); acc[1].w = fmaf(a1, w.w, acc[1].w);
                acc[2].x = fmaf(a2, w.x, acc[2].x); acc[2].y = fmaf(a2, w.y, acc[2].y);
                acc[2].z = fmaf(a2, w.z, acc[2].z); acc[2].w = fmaf(a2, w.w, acc[2].w);
                acc[3].x = fmaf(a3, w.x, acc[3].x); acc[3].y = fmaf(a3, w.y, acc[3].y);
                acc[3].z = fmaf(a3, w.z, acc[3].z); acc[3].w = fmaf(a3, w.w, acc[3].w);
                acc2[0].x = fmaf(a0, w2.x, acc2[0].x); acc2[0].y = fmaf(a0, w2.y, acc2[0].y);
                acc2[0].z = fmaf(a0, w2.z, acc2[0].z); acc2[0].w = fmaf(a0, w2.w, acc2[0].w);
                acc2[1].x = fmaf(a1, w2.x, acc2[1].x); acc2[1].y = fmaf(a1, w2.y, acc2[1].y);
                acc2[1].z = fmaf(a1, w2.z, acc2[1].z); acc2[1].w = fmaf(a1, w2.w, acc2[1].w);
                acc2[2].x = fmaf(a2, w2.x, acc2[2].x); acc2[2].y = fmaf(a2, w2.y, acc2[2].y);
                acc2[2].z = fmaf(a2, w2.z, acc2[2].z); acc2[2].w = fmaf(a2, w2.w, acc2[2].w);
                acc2[3].x = fmaf(a3, w2.x, acc2[3].x); acc2[3].y = fmaf(a3, w2.y, acc2[3].y);
                acc2[3].z = fmaf(a3, w2.z, acc2[3].z); acc2[3].w = fmaf(a3, w2.w, acc2[3].w);
            }
        } else {
            #pragma unroll 8
            for (int k = 0; k < 64; k++) {
                float4 w = *(const float4*)(Ws + k * 64 + col4);
                float a0 = As[(rowq * 4 + 0) * 68 + k];
                float a1 = As[(rowq * 4 + 1) * 68 + k];
                float a2 = As[(rowq * 4 + 2) * 68 + k];
                float a3 = As[(rowq * 4 + 3) * 68 + k];
                acc[0].x = fmaf(a0, w.x, acc[0].x); acc[0].y = fmaf(a0, w.y, acc[0].y);
                acc[0].z = fmaf(a0, w.z, acc[0].z); acc[0].w = fmaf(a0, w.w, acc[0].w);
                acc[1].x = fmaf(a1, w.x, acc[1].x); acc[1].y = fmaf(a1, w.y, acc[1].y);
                acc[1].z = fmaf(a1, w.z, acc[1].z); acc[1].w = fmaf(a1, w.w, acc[1].w);
                acc[2].x = fmaf(a2, w.x, acc[2].x); acc[2].y = fmaf(a2, w.y, acc[2].y);
                acc[2].z = fmaf(a2, w.z, acc[2].z); acc[2].w = fmaf(a2, w.w, acc[2].w);
                acc[3].x = fmaf(a3, w.x, acc[3].x); acc[3].y = fmaf(a3, w.y, acc[3].y);
                acc[3].z = fmaf(a3, w.z, acc[3].z); acc[3].w = fmaf(a3, w.w, acc[3].w);
            }
        }
        __syncthreads();
        if (more) {
            #pragma unroll
            for (int i = 0; i < 4; i++)
                *(float4*)(Ws + (size_t)(i * 256 + tid) * 4) = wreg[i];
            #pragma unroll
            for (int rr = 0; rr < 4; rr++)
                *(float4*)(As + (size_t)(rowq + rr * 16) * 68 + col4) = areg[rr];
            __syncthreads();
        }
    }

    #pragma unroll
    for (int r = 0; r < 4; r++) {
        int row = base + rowq * 4 + r;
        if (row < n) {
            float s = disq[row];
            float4 o;
            o.x = acc[r].x * s; o.y = acc[r].y * s;
            o.z = acc[r].z * s; o.w = acc[r].w * s;
            *(float4*)(C + (size_t)row * 64 + col4) = o;
            if (jk_mode == 1) {
                *(float4*)(jkacc + (size_t)row * 64 + col4) = acc2[r];
            } else if (jk_mode == 2) {
                float4 p = *(const float4*)(jkacc + (size_t)row * 64 + col4);
                p.x += acc2[r].x; p.y += acc2[r].y;
                p.z += acc2[r].z; p.w += acc2[r].w;
                *(float4*)(jkacc + (size_t)row * 64 + col4) = p;
            }
        }
    }
}

// ============ gather: wave per node, 16 lanes x float4, 4 edge slots ============
__global__ __launch_bounds__(256) void k_gather(
    const int* __restrict__ rowptr, const int* __restrict__ csr,
    const float* __restrict__ hW, const float* __restrict__ disq,
    const float* __restrict__ bias, float* __restrict__ hout, int n)
{
    const float4* hW4 = (const float4*)hW;
    int wid  = (blockIdx.x * 256 + threadIdx.x) >> 6;
    if (wid >= n) return;
    int lane = threadIdx.x & 63;
    int fb = lane & 15;       // feature float4 index
    int es = lane >> 4;       // edge slot 0..3
    int j  = rowptr[wid];
    int r1 = rowptr[wid + 1];
    float4 v  = make_float4(0.f, 0.f, 0.f, 0.f);
    float4 v2 = make_float4(0.f, 0.f, 0.f, 0.f);
    if (es == 0) v = hW4[(size_t)wid * 16 + fb];    // self-loop
    while (j < r1) {
        int cnt = min(r1 - j, 64);
        int idx = (lane < cnt) ? csr[j + lane] : 0;
        int jj = 0;
        for (; jj + 8 <= cnt; jj += 8) {
            int s0 = __shfl(idx, jj + es);
            int s1 = __shfl(idx, jj + 4 + es);
            float4 t0 = hW4[(size_t)s0 * 16 + fb];
            float4 t1 = hW4[(size_t)s1 * 16 + fb];
            v.x  += t0.x; v.y  += t0.y; v.z  += t0.z; v.w  += t0.w;
            v2.x += t1.x; v2.y += t1.y; v2.z += t1.z; v2.w += t1.w;
        }
        // tail: remainder cnt-jj in [0,7], 4 slots per step -> up to 2 steps
        for (; jj < cnt; jj += 4) {
            int sidx = jj + es;
            int s = __shfl(idx, (sidx < cnt) ? sidx : 0);
            if (sidx < cnt) {
                float4 t = hW4[(size_t)s * 16 + fb];
                v.x += t.x; v.y += t.y; v.z += t.z; v.w += t.w;
            }
        }
        j += cnt;
    }
    v.x += v2.x; v.y += v2.y; v.z += v2.z; v.w += v2.w;
    v.x += __shfl_xor(v.x, 16); v.y += __shfl_xor(v.y, 16);
    v.z += __shfl_xor(v.z, 16); v.w += __shfl_xor(v.w, 16);
    v.x += __shfl_xor(v.x, 32); v.y += __shfl_xor(v.y, 32);
    v.z += __shfl_xor(v.z, 32); v.w += __shfl_xor(v.w, 32);
    if (es == 0) {
        float s = disq[wid];
        float4 b = ((const float4*)bias)[fb];
        float4 o;
        o.x = fmaxf(fmaf(s, v.x, b.x), 0.f);
        o.y = fmaxf(fmaf(s, v.y, b.y), 0.f);
        o.z = fmaxf(fmaf(s, v.z, b.z), 0.f);
        o.w = fmaxf(fmaf(s, v.w, b.w), 0.f);
        ((float4*)hout)[(size_t)wid * 16 + fb] = o;
    }
}

// ============ final: t = h@jkW5 + jkacc + jkb; relu; pool by batch ============
__global__ __launch_bounds__(256) void k_jkfin_pool(
    const float* __restrict__ A,
    const float* __restrict__ W,
    const float* __restrict__ jkacc,
    const float* __restrict__ bias,
    const int* __restrict__ batch,
    float* __restrict__ pooled,
    int n)
{
    __shared__ float Ws[64 * 64];
    __shared__ float As[64 * 68];
    const int tid  = threadIdx.x;
    const int col4 = (tid & 15) * 4;
    const int rowq = tid >> 4;
    const int base = blockIdx.x * 64;

    #pragma unroll
    for (int i = 0; i < 4; i++) {
        float4 v = *(const float4*)(W + (size_t)(i * 256 + tid) * 4);
        *(float4*)(Ws + (size_t)(i * 256 + tid) * 4) = v;
    }
    #pragma unroll
    for (int rr = 0; rr < 4; rr++) {
        int row = base + rowq + rr * 16;
        float4 v = make_float4(0.f, 0.f, 0.f, 0.f);
        if (row < n) v = *(const float4*)(A + (size_t)row * 64 + col4);
        *(float4*)(As + (size_t)(rowq + rr * 16) * 68 + col4) = v;
    }
    __syncthreads();

    float4 acc[4];
    #pragma unroll
    for (int r = 0; r < 4; r++) acc[r] = make_float4(0.f, 0.f, 0.f, 0.f);
    #pragma unroll 8
    for (int k = 0; k < 64; k++) {
        float4 w = *(const float4*)(Ws + k * 64 + col4);
        float a0 = As[(rowq * 4 + 0) * 68 + k];
        float a1 = As[(rowq * 4 + 1) * 68 + k];
        float a2 = As[(rowq * 4 + 2) * 68 + k];
        float a3 = As[(rowq * 4 + 3) * 68 + k];
        acc[0].x = fmaf(a0, w.x, acc[0].x); acc[0].y = fmaf(a0, w.y, acc[0].y);
        acc[0].z = fmaf(a0, w.z, acc[0].z); acc[0].w = fmaf(a0, w.w, acc[0].w);
        acc[1].x = fmaf(a1, w.x, acc[1].x); acc[1].y = fmaf(a1, w.y, acc[1].y);
        acc[1].z = fmaf(a1, w.z, acc[1].z); acc[1].w = fmaf(a1, w.w, acc[1].w);
        acc[2].x = fmaf(a2, w.x, acc[2].x); acc[2].y = fmaf(a2, w.y, acc[2].y);
        acc[2].z = fmaf(a2, w.z, acc[2].z); acc[2].w = fmaf(a2, w.w, acc[2].w);
        acc[3].x = fmaf(a3, w.x, acc[3].x); acc[3].y = fmaf(a3, w.y, acc[3].y);
        acc[3].z = fmaf(a3, w.z, acc[3].z); acc[3].w = fmaf(a3, w.w, acc[3].w);
    }

    float4 bb = *(const float4*)(bias + col4);
    int curg = -1;
    float4 s4 = make_float4(0.f, 0.f, 0.f, 0.f);
    #pragma unroll
    for (int r = 0; r < 4; r++) {
        int row = base + rowq * 4 + r;
        if (row < n) {
            float4 p = *(const float4*)(jkacc + (size_t)row * 64 + col4);
            float4 vv;
            vv.x = fmaxf(acc[r].x + p.x + bb.x, 0.f);
            vv.y = fmaxf(acc[r].y + p.y + bb.y, 0.f);
            vv.z = fmaxf(acc[r].z + p.z + bb.z, 0.f);
            vv.w = fmaxf(acc[r].w + p.w + bb.w, 0.f);
            int g = batch[row];
            if (g != curg) {
                if (curg >= 0) {
                    atomicAdd(&pooled[curg * 64 + col4 + 0], s4.x);
                    atomicAdd(&pooled[curg * 64 + col4 + 1], s4.y);
                    atomicAdd(&pooled[curg * 64 + col4 + 2], s4.z);
                    atomicAdd(&pooled[curg * 64 + col4 + 3], s4.w);
                }
                curg = g; s4 = vv;
            } else {
                s4.x += vv.x; s4.y += vv.y; s4.z += vv.z; s4.w += vv.w;
            }
        }
    }
    if (curg >= 0) {
        atomicAdd(&pooled[curg * 64 + col4 + 0], s4.x);
        atomicAdd(&pooled[curg * 64 + col4 + 1], s4.y);
        atomicAdd(&pooled[curg * 64 + col4 + 2], s4.z);
        atomicAdd(&pooled[curg * 64 + col4 + 3], s4.w);
    }
}

// ============ head ============
__global__ void k_head(
    const float* __restrict__ pooled,
    const float* __restrict__ W1, const float* __restrict__ b1,
    const float* __restrict__ W2, const float* __restrict__ b2,
    float* __restrict__ out)
{
    int g = threadIdx.x;
    float p[64];
    #pragma unroll
    for (int k = 0; k < 64; k++) p[k] = pooled[g * 64 + k];
    float h1[64];
    #pragma unroll
    for (int j = 0; j < 64; j++) {
        float acc = b1[j];
        #pragma unroll
        for (int k = 0; k < 64; k++) acc = fmaf(p[k], W1[k * 64 + j], acc);
        h1[j] = fmaxf(acc, 0.f);
    }
    float lg[10];
    float mx = -1e30f;
    #pragma unroll
    for (int c = 0; c < 10; c++) {
        float acc = b2[c];
        #pragma unroll
        for (int j = 0; j < 64; j++) acc = fmaf(h1[j], W2[j * 10 + c], acc);
        lg[c] = acc;
        mx = fmaxf(mx, acc);
    }
    float ssum = 0.f;
    #pragma unroll
    for (int c = 0; c < 10; c++) { lg[c] = __expf(lg[c] - mx); ssum += lg[c]; }
    float inv = 1.0f / ssum;
    #pragma unroll
    for (int c = 0; c < 10; c++) out[g * 10 + c] = lg[c] * inv;
}

extern "C" void kernel_launch(void* const* d_in, const int* in_sizes, int n_in,
                              void* d_out, int out_size, void* d_ws, size_t ws_size,
                              hipStream_t stream) {
    (void)in_sizes; (void)n_in; (void)out_size; (void)ws_size;
    const float* x     = (const float*)d_in[0];
    const int*   ei    = (const int*)d_in[1];
    const int*   batch = (const int*)d_in[2];
    const float* W0    = (const float*)d_in[3];
    const float* b0    = (const float*)d_in[4];
    const float* Wh    = (const float*)d_in[5];
    const float* bh    = (const float*)d_in[6];
    const float* jkW   = (const float*)d_in[7];   // [384][64] = 6 stacked [64][64]
    const float* jkb   = (const float*)d_in[8];
    const float* W1    = (const float*)d_in[9];
    const float* b1    = (const float*)d_in[10];
    const float* W2    = (const float*)d_in[11];
    const float* b2    = (const float*)d_in[12];

    const int* src = ei;
    const int* dst = ei + NE;

    float* fws    = (float*)d_ws;
    float* disq   = fws;
    float* hWb    = disq + 100352;
    float* h      = hWb + (size_t)NN * 64;
    float* jkacc  = h + (size_t)NN * 64;
    float* pooled = jkacc + (size_t)NN * 64;
    int*   counts = (int*)(pooled + 4096);
    int*   rowptr = counts + 100352;
    int*   wptr   = rowptr + 100352;
    int*   bsum   = wptr + 100352;
    int*   csr    = bsum + 512;

    const int NB_N = (NN + 255) / 256;
    const int NB_E = (NE + 255) / 256;

    hipMemsetAsync(counts, 0, (size_t)NN * sizeof(int), stream);
    k_hist<<<NB_E, 256, 0, stream>>>(dst, counts, NE);
    k_blocksum<<<NB_N, 256, 0, stream>>>(counts, bsum, NN);
    k_scanbsum<<<1, 512, 0, stream>>>(bsum, NB_N);
    k_scanwrite<<<NB_N, 256, 0, stream>>>(counts, bsum, rowptr, wptr, disq, NN, NE);
    k_scatter<<<NB_E, 256, 0, stream>>>(src, dst, wptr, csr, NE);

    const int gemm_grid   = (NN + 63) / 64;
    const int gather_grid = (NN + 3) / 4;
    for (int l = 0; l < NLAY; l++) {
        const float* A    = (l == 0) ? x : h;
        int          lda  = (l == 0) ? F_INF : HID;
        int          K    = (l == 0) ? F_INF : HID;
        const float* W    = (l == 0) ? W0 : (Wh + (size_t)(l - 1) * 64 * 64);
        const float* bias = (l == 0) ? b0 : (bh + (size_t)(l - 1) * 64);
        const float* jw   = (l == 0) ? nullptr : (jkW + (size_t)(l - 1) * 64 * 64);
        int          jkm  = (l == 0) ? 0 : ((l == 1) ? 1 : 2);

        k_gemm_dual<<<gemm_grid, 256, 0, stream>>>(A, lda, K, W, jw, disq,
                                                   hWb, jkacc, jkm, NN);
        k_gather<<<gather_grid, 256, 0, stream>>>(rowptr, csr, hWb, disq, bias, h, NN);
    }

    hipMemsetAsync(pooled, 0, 64 * 64 * sizeof(float), stream);
    k_jkfin_pool<<<gemm_grid, 256, 0, stream>>>(h, jkW + (size_t)5 * 64 * 64, jkacc,
                                                jkb, batch, pooled, NN);
    k_head<<<1, 64, 0, stream>>>(pooled, W1, b1, W2, b2, (float*)d_out);
}

// Round 5
// 650.978 us; speedup vs baseline: 2.7246x; 1.1421x over previous
//
#include <hip/hip_runtime.h>

#define NN 100000
#define NE 1000000
#define F_INF 128
#define HID 64
#define NLAY 6
#define NCLS 10
#define NGRAPH 64

// ================= CSR build =================
__global__ void k_hist(const int* __restrict__ dst, int* __restrict__ counts, int e) {
    int i = blockIdx.x * 256 + threadIdx.x;
    if (i < e) atomicAdd(&counts[dst[i]], 1);
}

__global__ void k_blocksum(const int* __restrict__ counts, int* __restrict__ bsum, int n) {
    int i = blockIdx.x * 256 + threadIdx.x;
    int v = (i < n) ? counts[i] : 0;
    #pragma unroll
    for (int off = 32; off >= 1; off >>= 1) v += __shfl_down(v, off);
    __shared__ int ws[4];
    if ((threadIdx.x & 63) == 0) ws[threadIdx.x >> 6] = v;
    __syncthreads();
    if (threadIdx.x == 0) bsum[blockIdx.x] = ws[0] + ws[1] + ws[2] + ws[3];
}

__global__ void k_scanbsum(int* __restrict__ bsum, int nb) {   // 1 block, 512 thr
    __shared__ int sh[512];
    int t = threadIdx.x;
    int v = (t < nb) ? bsum[t] : 0;
    sh[t] = v; __syncthreads();
    for (int off = 1; off < 512; off <<= 1) {
        int x = (t >= off) ? sh[t - off] : 0;
        __syncthreads();
        sh[t] += x; __syncthreads();
    }
    if (t < nb) bsum[t] = sh[t] - v;   // exclusive
}

__global__ void k_scanwrite(const int* __restrict__ counts, const int* __restrict__ bsumx,
                            int* __restrict__ rowptr, int* __restrict__ wptr,
                            float* __restrict__ disq, int n, int e) {
    __shared__ int sh[256];
    int t = threadIdx.x;
    int i = blockIdx.x * 256 + t;
    int v = (i < n) ? counts[i] : 0;
    sh[t] = v; __syncthreads();
    for (int off = 1; off < 256; off <<= 1) {
        int x = (t >= off) ? sh[t - off] : 0;
        __syncthreads();
        sh[t] += x; __syncthreads();
    }
    int excl = sh[t] - v + bsumx[blockIdx.x];
    if (i < n) {
        rowptr[i] = excl;
        wptr[i]   = excl;
        disq[i]   = rsqrtf((float)(v + 1));   // +1 self-loop
    }
    if (i == 0) rowptr[n] = e;
}

__global__ void k_scatter(const int* __restrict__ src, const int* __restrict__ dst,
                          int* __restrict__ wptr, int* __restrict__ csr, int e) {
    int i = blockIdx.x * 256 + threadIdx.x;
    if (i < e) {
        int pos = atomicAdd(&wptr[dst[i]], 1);
        csr[pos] = src[i];
    }
}

// ============ dual GEMM: C = (A@W)*disq[row]; optionally jkacc (+)= A@jkw ============
__global__ __launch_bounds__(256) void k_gemm_dual(
    const float* __restrict__ A, int lda, int K,
    const float* __restrict__ W,
    const float* __restrict__ jkw,
    const float* __restrict__ disq,
    float* __restrict__ C,
    float* __restrict__ jkacc,
    int jk_mode, int n)
{
    __shared__ float Ws[64 * 64];
    __shared__ float Ws2[64 * 64];
    __shared__ float As[64 * 68];
    const int tid  = threadIdx.x;
    const int col4 = (tid & 15) * 4;
    const int rowq = tid >> 4;
    const int base = blockIdx.x * 64;

    {
        #pragma unroll
        for (int i = 0; i < 4; i++) {
            float4 v = *(const float4*)(W + (size_t)(i * 256 + tid) * 4);
            *(float4*)(Ws + (size_t)(i * 256 + tid) * 4) = v;
        }
        if (jk_mode) {
            #pragma unroll
            for (int i = 0; i < 4; i++) {
                float4 v = *(const float4*)(jkw + (size_t)(i * 256 + tid) * 4);
                *(float4*)(Ws2 + (size_t)(i * 256 + tid) * 4) = v;
            }
        }
        #pragma unroll
        for (int rr = 0; rr < 4; rr++) {
            int row = base + rowq + rr * 16;
            float4 v = make_float4(0.f, 0.f, 0.f, 0.f);
            if (row < n) v = *(const float4*)(A + (size_t)row * lda + col4);
            *(float4*)(As + (size_t)(rowq + rr * 16) * 68 + col4) = v;
        }
    }
    __syncthreads();

    float4 acc[4], acc2[4];
    #pragma unroll
    for (int r = 0; r < 4; r++) {
        acc[r]  = make_float4(0.f, 0.f, 0.f, 0.f);
        acc2[r] = make_float4(0.f, 0.f, 0.f, 0.f);
    }

    for (int k0 = 0; k0 < K; k0 += 64) {
        const bool more = (k0 + 64) < K;
        float4 wreg[4], areg[4];
        if (more) {
            #pragma unroll
            for (int i = 0; i < 4; i++)
                wreg[i] = *(const float4*)(W + (size_t)(k0 + 64) * 64 + (i * 256 + tid) * 4);
            #pragma unroll
            for (int rr = 0; rr < 4; rr++) {
                int row = base + rowq + rr * 16;
                areg[rr] = make_float4(0.f, 0.f, 0.f, 0.f);
                if (row < n) areg[rr] = *(const float4*)(A + (size_t)row * lda + k0 + 64 + col4);
            }
        }
        if (jk_mode && k0 == 0) {
            #pragma unroll 4
            for (int k = 0; k < 64; k++) {
                float4 w  = *(const float4*)(Ws  + k * 64 + col4);
                float4 w2 = *(const float4*)(Ws2 + k * 64 + col4);
                float a0 = As[(rowq * 4 + 0) * 68 + k];
                float a1 = As[(rowq * 4 + 1) * 68 + k];
                float a2 = As[(rowq * 4 + 2) * 68 + k];
                float a3 = As[(rowq * 4 + 3) * 68 + k];
                acc[0].x = fmaf(a0, w.x, acc[0].x); acc[0].y = fmaf(a0, w.y, acc[0].y);
                acc[0].z = fmaf(a0, w.z, acc[0].z); acc[0].w = fmaf(a0, w.w, acc[0].w);
                acc[1].x = fmaf(a1, w.x, acc[1].x); acc[1].y = fmaf(a1, w.y, acc[1].y);
                acc[1].z = fmaf(a1, w.z, acc[1].z); acc[1].w = fmaf(a1, w.w, acc[1].w);
                acc[2].x = fmaf(a2, w.x, acc[2].x); acc[2].y = fmaf(a2, w.y, acc[2].y);
                acc[2].z = fmaf(a2, w.z, acc[2].z); acc[2].w = fmaf(a2, w.w, acc[2].w);
                acc[3].x = fmaf(a3, w.x, acc[3].x); acc[3].y = fmaf(a3, w.y, acc[3].y);
                acc[3].z = fmaf(a3, w.z, acc[3].z); acc[3].w = fmaf(a3, w.w, acc[3].w);
                acc2[0].x = fmaf(a0, w2.x, acc2[0].x); acc2[0].y = fmaf(a0, w2.y, acc2[0].y);
                acc2[0].z = fmaf(a0, w2.z, acc2[0].z); acc2[0].w = fmaf(a0, w2.w, acc2[0].w);
                acc2[1].x = fmaf(a1, w2.x, acc2[1].x); acc2[1].y = fmaf(a1, w2.y, acc2[1].y);
                acc2[1].z = fmaf(a1, w2.z, acc2[1].z); acc2[1].w = fmaf(a1, w2.w, acc2[1].w);
                acc2[2].x = fmaf(a2, w2.x, acc2[2].x); acc2[2].y = fmaf(a2, w2.y, acc2[2].y);
                acc2[2].z = fmaf(a2, w2.z, acc2[2].z); acc2[2].w = fmaf(a2, w2.w, acc2[2].w);
                acc2[3].x = fmaf(a3, w2.x, acc2[3].x); acc2[3].y = fmaf(a3, w2.y, acc2[3].y);
                acc2[3].z = fmaf(a3, w2.z, acc2[3].z); acc2[3].w = fmaf(a3, w2.w, acc2[3].w);
            }
        } else {
            #pragma unroll 8
            for (int k = 0; k < 64; k++) {
                float4 w = *(const float4*)(Ws + k * 64 + col4);
                float a0 = As[(rowq * 4 + 0) * 68 + k];
                float a1 = As[(rowq * 4 + 1) * 68 + k];
                float a2 = As[(rowq * 4 + 2) * 68 + k];
                float a3 = As[(rowq * 4 + 3) * 68 + k];
                acc[0].x = fmaf(a0, w.x, acc[0].x); acc[0].y = fmaf(a0, w.y, acc[0].y);
                acc[0].z = fmaf(a0, w.z, acc[0].z); acc[0].w = fmaf(a0, w.w, acc[0].w);
                acc[1].x = fmaf(a1, w.x, acc[1].x); acc[1].y = fmaf(a1, w.y, acc[1].y);
                acc[1].z = fmaf(a1, w.z, acc[1].z); acc[1].w = fmaf(a1, w.w, acc[1].w);
                acc[2].x = fmaf(a2, w.x, acc[2].x); acc[2].y = fmaf(a2, w.y, acc[2].y);
                acc[2].z = fmaf(a2, w.z, acc[2].z); acc[2].w = fmaf(a2, w.w, acc[2].w);
                acc[3].x = fmaf(a3, w.x, acc[3].x); acc[3].y = fmaf(a3, w.y, acc[3].y);
                acc[3].z = fmaf(a3, w.z, acc[3].z); acc[3].w = fmaf(a3, w.w, acc[3].w);
            }
        }
        __syncthreads();
        if (more) {
            #pragma unroll
            for (int i = 0; i < 4; i++)
                *(float4*)(Ws + (size_t)(i * 256 + tid) * 4) = wreg[i];
            #pragma unroll
            for (int rr = 0; rr < 4; rr++)
                *(float4*)(As + (size_t)(rowq + rr * 16) * 68 + col4) = areg[rr];
            __syncthreads();
        }
    }

    #pragma unroll
    for (int r = 0; r < 4; r++) {
        int row = base + rowq * 4 + r;
        if (row < n) {
            float s = disq[row];
            float4 o;
            o.x = acc[r].x * s; o.y = acc[r].y * s;
            o.z = acc[r].z * s; o.w = acc[r].w * s;
            *(float4*)(C + (size_t)row * 64 + col4) = o;
            if (jk_mode == 1) {
                *(float4*)(jkacc + (size_t)row * 64 + col4) = acc2[r];
            } else if (jk_mode == 2) {
                float4 p = *(const float4*)(jkacc + (size_t)row * 64 + col4);
                p.x += acc2[r].x; p.y += acc2[r].y;
                p.z += acc2[r].z; p.w += acc2[r].w;
                *(float4*)(jkacc + (size_t)row * 64 + col4) = p;
            }
        }
    }
}

// ============ gather: wave per node, 16 lanes x float4, 4 edge slots ============
__global__ __launch_bounds__(256) void k_gather(
    const int* __restrict__ rowptr, const int* __restrict__ csr,
    const float* __restrict__ hW, const float* __restrict__ disq,
    const float* __restrict__ bias, float* __restrict__ hout, int n)
{
    const float4* hW4 = (const float4*)hW;
    int wid  = (blockIdx.x * 256 + threadIdx.x) >> 6;
    if (wid >= n) return;
    int lane = threadIdx.x & 63;
    int fb = lane & 15;       // feature float4 index
    int es = lane >> 4;       // edge slot 0..3
    int j  = rowptr[wid];
    int r1 = rowptr[wid + 1];
    float4 v  = make_float4(0.f, 0.f, 0.f, 0.f);
    float4 v2 = make_float4(0.f, 0.f, 0.f, 0.f);
    if (es == 0) v = hW4[(size_t)wid * 16 + fb];    // self-loop
    while (j < r1) {
        int cnt = min(r1 - j, 64);
        int idx = (lane < cnt) ? csr[j + lane] : 0;
        int jj = 0;
        for (; jj + 8 <= cnt; jj += 8) {
            int s0 = __shfl(idx, jj + es);
            int s1 = __shfl(idx, jj + 4 + es);
            float4 t0 = hW4[(size_t)s0 * 16 + fb];
            float4 t1 = hW4[(size_t)s1 * 16 + fb];
            v.x  += t0.x; v.y  += t0.y; v.z  += t0.z; v.w  += t0.w;
            v2.x += t1.x; v2.y += t1.y; v2.z += t1.z; v2.w += t1.w;
        }
        // tail: remainder cnt-jj in [0,7], 4 slots per step -> up to 2 steps
        for (; jj < cnt; jj += 4) {
            int sidx = jj + es;
            int s = __shfl(idx, (sidx < cnt) ? sidx : 0);
            if (sidx < cnt) {
                float4 t = hW4[(size_t)s * 16 + fb];
                v.x += t.x; v.y += t.y; v.z += t.z; v.w += t.w;
            }
        }
        j += cnt;
    }
    v.x += v2.x; v.y += v2.y; v.z += v2.z; v.w += v2.w;
    v.x += __shfl_xor(v.x, 16); v.y += __shfl_xor(v.y, 16);
    v.z += __shfl_xor(v.z, 16); v.w += __shfl_xor(v.w, 16);
    v.x += __shfl_xor(v.x, 32); v.y += __shfl_xor(v.y, 32);
    v.z += __shfl_xor(v.z, 32); v.w += __shfl_xor(v.w, 32);
    if (es == 0) {
        float s = disq[wid];
        float4 b = ((const float4*)bias)[fb];
        float4 o;
        o.x = fmaxf(fmaf(s, v.x, b.x), 0.f);
        o.y = fmaxf(fmaf(s, v.y, b.y), 0.f);
        o.z = fmaxf(fmaf(s, v.z, b.z), 0.f);
        o.w = fmaxf(fmaf(s, v.w, b.w), 0.f);
        ((float4*)hout)[(size_t)wid * 16 + fb] = o;
    }
}

// ============ final: t = relu(h@jkW5 + jkacc + jkb); pool by batch (LDS pre-reduce) ============
__global__ __launch_bounds__(256) void k_jkfin_pool(
    const float* __restrict__ A,
    const float* __restrict__ W,
    const float* __restrict__ jkacc,
    const float* __restrict__ bias,
    const int* __restrict__ batch,
    float* __restrict__ pooled,
    int n)
{
    __shared__ float Ws[64 * 64];
    __shared__ float As[64 * 68];
    const int tid  = threadIdx.x;
    const int col4 = (tid & 15) * 4;
    const int rowq = tid >> 4;
    const int base = blockIdx.x * 64;

    #pragma unroll
    for (int i = 0; i < 4; i++) {
        float4 v = *(const float4*)(W + (size_t)(i * 256 + tid) * 4);
        *(float4*)(Ws + (size_t)(i * 256 + tid) * 4) = v;
    }
    #pragma unroll
    for (int rr = 0; rr < 4; rr++) {
        int row = base + rowq + rr * 16;
        float4 v = make_float4(0.f, 0.f, 0.f, 0.f);
        if (row < n) v = *(const float4*)(A + (size_t)row * 64 + col4);
        *(float4*)(As + (size_t)(rowq + rr * 16) * 68 + col4) = v;
    }
    __syncthreads();

    float4 acc[4];
    #pragma unroll
    for (int r = 0; r < 4; r++) acc[r] = make_float4(0.f, 0.f, 0.f, 0.f);
    #pragma unroll 8
    for (int k = 0; k < 64; k++) {
        float4 w = *(const float4*)(Ws + k * 64 + col4);
        float a0 = As[(rowq * 4 + 0) * 68 + k];
        float a1 = As[(rowq * 4 + 1) * 68 + k];
        float a2 = As[(rowq * 4 + 2) * 68 + k];
        float a3 = As[(rowq * 4 + 3) * 68 + k];
        acc[0].x = fmaf(a0, w.x, acc[0].x); acc[0].y = fmaf(a0, w.y, acc[0].y);
        acc[0].z = fmaf(a0, w.z, acc[0].z); acc[0].w = fmaf(a0, w.w, acc[0].w);
        acc[1].x = fmaf(a1, w.x, acc[1].x); acc[1].y = fmaf(a1, w.y, acc[1].y);
        acc[1].z = fmaf(a1, w.z, acc[1].z); acc[1].w = fmaf(a1, w.w, acc[1].w);
        acc[2].x = fmaf(a2, w.x, acc[2].x); acc[2].y = fmaf(a2, w.y, acc[2].y);
        acc[2].z = fmaf(a2, w.z, acc[2].z); acc[2].w = fmaf(a2, w.w, acc[2].w);
        acc[3].x = fmaf(a3, w.x, acc[3].x); acc[3].y = fmaf(a3, w.y, acc[3].y);
        acc[3].z = fmaf(a3, w.z, acc[3].z); acc[3].w = fmaf(a3, w.w, acc[3].w);
    }
    __syncthreads();               // Ws/As dead; reuse Ws as the pooling slab

    float* slab = Ws;              // [64 graphs][64 cols]
    #pragma unroll
    for (int i = tid; i < 4096; i += 256) slab[i] = 0.f;
    __syncthreads();

    float4 bb = *(const float4*)(bias + col4);
    int curg = -1;
    float4 s4 = make_float4(0.f, 0.f, 0.f, 0.f);
    #pragma unroll
    for (int r = 0; r < 4; r++) {
        int row = base + rowq * 4 + r;
        if (row < n) {
            float4 p = *(const float4*)(jkacc + (size_t)row * 64 + col4);
            float4 vv;
            vv.x = fmaxf(acc[r].x + p.x + bb.x, 0.f);
            vv.y = fmaxf(acc[r].y + p.y + bb.y, 0.f);
            vv.z = fmaxf(acc[r].z + p.z + bb.z, 0.f);
            vv.w = fmaxf(acc[r].w + p.w + bb.w, 0.f);
            int g = batch[row];
            if (g != curg) {
                if (curg >= 0) {
                    atomicAdd(&slab[curg * 64 + col4 + 0], s4.x);
                    atomicAdd(&slab[curg * 64 + col4 + 1], s4.y);
                    atomicAdd(&slab[curg * 64 + col4 + 2], s4.z);
                    atomicAdd(&slab[curg * 64 + col4 + 3], s4.w);
                }
                curg = g; s4 = vv;
            } else {
                s4.x += vv.x; s4.y += vv.y; s4.z += vv.z; s4.w += vv.w;
            }
        }
    }
    if (curg >= 0) {
        atomicAdd(&slab[curg * 64 + col4 + 0], s4.x);
        atomicAdd(&slab[curg * 64 + col4 + 1], s4.y);
        atomicAdd(&slab[curg * 64 + col4 + 2], s4.z);
        atomicAdd(&slab[curg * 64 + col4 + 3], s4.w);
    }
    __syncthreads();

    // flush only the graph range this block touched: ~1-3 graphs
    int g0 = batch[base];
    int g1 = batch[(base + 63 < n) ? (base + 63) : (n - 1)];
    int cnt = (g1 - g0 + 1) * 64;
    for (int i = tid; i < cnt; i += 256) {
        int g = g0 + (i >> 6);
        int c = i & 63;
        float v = slab[g * 64 + c];
        if (v != 0.f) atomicAdd(&pooled[g * 64 + c], v);
    }
}

// ============ head ============
__global__ void k_head(
    const float* __restrict__ pooled,
    const float* __restrict__ W1, const float* __restrict__ b1,
    const float* __restrict__ W2, const float* __restrict__ b2,
    float* __restrict__ out)
{
    int g = threadIdx.x;
    float p[64];
    #pragma unroll
    for (int k = 0; k < 64; k++) p[k] = pooled[g * 64 + k];
    float h1[64];
    #pragma unroll
    for (int j = 0; j < 64; j++) {
        float acc = b1[j];
        #pragma unroll
        for (int k = 0; k < 64; k++) acc = fmaf(p[k], W1[k * 64 + j], acc);
        h1[j] = fmaxf(acc, 0.f);
    }
    float lg[10];
    float mx = -1e30f;
    #pragma unroll
    for (int c = 0; c < 10; c++) {
        float acc = b2[c];
        #pragma unroll
        for (int j = 0; j < 64; j++) acc = fmaf(h1[j], W2[j * 10 + c], acc);
        lg[c] = acc;
        mx = fmaxf(mx, acc);
    }
    float ssum = 0.f;
    #pragma unroll
    for (int c = 0; c < 10; c++) { lg[c] = __expf(lg[c] - mx); ssum += lg[c]; }
    float inv = 1.0f / ssum;
    #pragma unroll
    for (int c = 0; c < 10; c++) out[g * 10 + c] = lg[c] * inv;
}

extern "C" void kernel_launch(void* const* d_in, const int* in_sizes, int n_in,
                              void* d_out, int out_size, void* d_ws, size_t ws_size,
                              hipStream_t stream) {
    (void)in_sizes; (void)n_in; (void)out_size; (void)ws_size;
    const float* x     = (const float*)d_in[0];
    const int*   ei    = (const int*)d_in[1];
    const int*   batch = (const int*)d_in[2];
    const float* W0    = (const float*)d_in[3];
    const float* b0    = (const float*)d_in[4];
    const float* Wh    = (const float*)d_in[5];
    const float* bh    = (const float*)d_in[6];
    const float* jkW   = (const float*)d_in[7];   // [384][64] = 6 stacked [64][64]
    const float* jkb   = (const float*)d_in[8];
    const float* W1    = (const float*)d_in[9];
    const float* b1    = (const float*)d_in[10];
    const float* W2    = (const float*)d_in[11];
    const float* b2    = (const float*)d_in[12];

    const int* src = ei;
    const int* dst = ei + NE;

    float* fws    = (float*)d_ws;
    float* disq   = fws;
    float* hWb    = disq + 100352;
    float* h      = hWb + (size_t)NN * 64;
    float* jkacc  = h + (size_t)NN * 64;
    float* pooled = jkacc + (size_t)NN * 64;
    int*   counts = (int*)(pooled + 4096);
    int*   rowptr = counts + 100352;
    int*   wptr   = rowptr + 100352;
    int*   bsum   = wptr + 100352;
    int*   csr    = bsum + 512;

    const int NB_N = (NN + 255) / 256;
    const int NB_E = (NE + 255) / 256;

    hipMemsetAsync(counts, 0, (size_t)NN * sizeof(int), stream);
    k_hist<<<NB_E, 256, 0, stream>>>(dst, counts, NE);
    k_blocksum<<<NB_N, 256, 0, stream>>>(counts, bsum, NN);
    k_scanbsum<<<1, 512, 0, stream>>>(bsum, NB_N);
    k_scanwrite<<<NB_N, 256, 0, stream>>>(counts, bsum, rowptr, wptr, disq, NN, NE);
    k_scatter<<<NB_E, 256, 0, stream>>>(src, dst, wptr, csr, NE);

    const int gemm_grid   = (NN + 63) / 64;
    const int gather_grid = (NN + 3) / 4;
    for (int l = 0; l < NLAY; l++) {
        const float* A    = (l == 0) ? x : h;
        int          lda  = (l == 0) ? F_INF : HID;
        int          K    = (l == 0) ? F_INF : HID;
        const float* W    = (l == 0) ? W0 : (Wh + (size_t)(l - 1) * 64 * 64);
        const float* bias = (l == 0) ? b0 : (bh + (size_t)(l - 1) * 64);
        const float* jw   = (l == 0) ? nullptr : (jkW + (size_t)(l - 1) * 64 * 64);
        int          jkm  = (l == 0) ? 0 : ((l == 1) ? 1 : 2);

        k_gemm_dual<<<gemm_grid, 256, 0, stream>>>(A, lda, K, W, jw, disq,
                                                   hWb, jkacc, jkm, NN);
        k_gather<<<gather_grid, 256, 0, stream>>>(rowptr, csr, hWb, disq, bias, h, NN);
    }

    hipMemsetAsync(pooled, 0, 64 * 64 * sizeof(float), stream);
    k_jkfin_pool<<<gemm_grid, 256, 0, stream>>>(h, jkW + (size_t)5 * 64 * 64, jkacc,
                                                jkb, batch, pooled, NN);
    k_head<<<1, 64, 0, stream>>>(pooled, W1, b1, W2, b2, (float*)d_out);
}